// Round 14
// baseline (569.614 us; speedup 1.0000x reference)
//
#include <hip/hip_runtime.h>
#include <hip/hip_bf16.h>

#define N_NODES 50000
#define N_EDGES 800000
#define FD 128
#define N_GRAPHS 256
#define NPART 6250   // N_NODES / 8 (nodes per XCD partition)

typedef unsigned short u16;
typedef short bf16x8 __attribute__((ext_vector_type(8)));
typedef float f32x4 __attribute__((ext_vector_type(4)));

__device__ __forceinline__ u16 f2bf(float v) {
    __hip_bfloat16 h = __float2bfloat16(v);
    union { __hip_bfloat16 hh; u16 u; } c; c.hh = h; return c.u;
}
__device__ __forceinline__ float bf2f(u16 r) {
    return __uint_as_float(((unsigned int)r) << 16);
}

// ---------------------------------------------------------------- CSR build (XCD-partitioned)
__global__ __launch_bounds__(256) void count_deg_part_k(const int* __restrict__ src,
                                                        int* __restrict__ cnt, int E) {
    int part = blockIdx.x & 7;
    int lo = part * NPART, hi = lo + NPART;
    int stride = (gridDim.x >> 3) * 256;
    for (int e = (blockIdx.x >> 3) * 256 + threadIdx.x; e < E; e += stride) {
        int s = src[e];
        if (s >= lo && s < hi) atomicAdd(&cnt[s], 1);
    }
}

__global__ __launch_bounds__(256) void fill_csr_part_k(const int* __restrict__ src,
                                                       const int* __restrict__ dst,
                                                       int* __restrict__ cur,
                                                       int* __restrict__ edst, int E) {
    int part = blockIdx.x & 7;
    int lo = part * NPART, hi = lo + NPART;
    int stride = (gridDim.x >> 3) * 256;
    for (int e = (blockIdx.x >> 3) * 256 + threadIdx.x; e < E; e += stride) {
        int s = src[e];
        if (s >= lo && s < hi) {
            int p = atomicAdd(&cur[s], 1);
            edst[p] = dst[e];
        }
    }
}

// per-256-chunk sums; block 0 also zeroes bnbuf (512 f) and pooled (32768 f)
__global__ __launch_bounds__(256) void scan1_k(const int* __restrict__ cnt,
                                               int* __restrict__ bsum, int M,
                                               float* __restrict__ bnbuf,
                                               float* __restrict__ pooled) {
    int i = blockIdx.x * 256 + threadIdx.x;
    int v = (i < M) ? cnt[i] : 0;
    __shared__ int l[256];
    l[threadIdx.x] = v;
    __syncthreads();
    for (int s = 128; s > 0; s >>= 1) {
        if (threadIdx.x < s) l[threadIdx.x] += l[threadIdx.x + s];
        __syncthreads();
    }
    if (threadIdx.x == 0) bsum[blockIdx.x] = l[0];
    if (blockIdx.x == 0) {
        bnbuf[threadIdx.x] = 0.f; bnbuf[threadIdx.x + 256] = 0.f;
        for (int k = threadIdx.x; k < N_GRAPHS * FD; k += 256) pooled[k] = 0.f;
    }
}

// local exclusive scan + redundant per-block scan of raw bsum (merged scan2)
__global__ __launch_bounds__(256) void scan3_k(const int* __restrict__ cnt,
                                               const int* __restrict__ bsum,
                                               int* __restrict__ offs,
                                               int* __restrict__ cur, int M, int NB) {
    int i = blockIdx.x * 256 + threadIdx.x;
    int tid = threadIdx.x;
    __shared__ int bs[256];
    bs[tid] = (tid < NB) ? bsum[tid] : 0;
    __syncthreads();
    for (int off = 1; off < 256; off <<= 1) {
        int t = (tid >= off) ? bs[tid - off] : 0;
        __syncthreads();
        bs[tid] += t;
        __syncthreads();
    }
    int base = (blockIdx.x == 0) ? 0 : bs[blockIdx.x - 1];
    int v = (i < M) ? cnt[i] : 0;
    __shared__ int l[256];
    l[tid] = v;
    __syncthreads();
    for (int off = 1; off < 256; off <<= 1) {
        int t = (tid >= off) ? l[tid - off] : 0;
        __syncthreads();
        l[tid] += t;
        __syncthreads();
    }
    int excl = l[tid] - v + base;
    if (i < M) { offs[i] = excl; cur[i] = excl; }
    if (i == M - 1) offs[M] = excl + v;
}

// ---------------------------------------------------------------- weight prep
// layer 1 (no affine): Wt[n][k] = bf16(W[k][n]); cvec = 0
__global__ __launch_bounds__(128) void wprep1_k(const float* __restrict__ W,
                                                u16* __restrict__ Wt,
                                                float* __restrict__ cvec) {
    int n = blockIdx.x, k = threadIdx.x;
    Wt[(size_t)n * FD + k] = f2bf(W[(size_t)k * FD + n]);
    if (k == 0) cvec[n] = 0.f;
}

// layers 2/3: BN finalize (redundant per block, from sums/sumsq) + weight fold
__global__ __launch_bounds__(128) void bnfw_k(const float* __restrict__ W,
                                              const float* __restrict__ sums,
                                              const float* __restrict__ sumsq,
                                              const float* __restrict__ g,
                                              const float* __restrict__ b,
                                              float invN,
                                              u16* __restrict__ Wt,
                                              float* __restrict__ cvec) {
    int n = blockIdx.x, k = threadIdx.x;
    __shared__ float scs[128], shs[128], l[128];
    float mu = sums[k] * invN;
    float var = sumsq[k] * invN - mu * mu;
    float sc = g[k] * rsqrtf(var + 1e-5f);
    scs[k] = sc;
    shs[k] = b[k] - mu * sc;
    __syncthreads();
    float w = W[(size_t)k * FD + n];
    Wt[(size_t)n * FD + k] = f2bf(scs[k] * w);
    l[k] = shs[k] * w;
    __syncthreads();
    for (int s = 64; s > 0; s >>= 1) {
        if (k < s) l[k] += l[k + s];
        __syncthreads();
    }
    if (k == 0) cvec[n] = l[0];
}

// ---------------------------------------------------------------- MFMA GEMM + dots
// H written into 4 quarter-planes: Hq[q*M*32 + node*32 + (f&31)], q = f>>5.
__global__ __launch_bounds__(256) void gemm_mfma_k(const float* __restrict__ Xf,
                                                   const u16* __restrict__ Xb,
                                                   int use_f32,
                                                   const u16* __restrict__ Wt,
                                                   const float* __restrict__ cvec,
                                                   const float* __restrict__ avec,
                                                   u16* __restrict__ Hq,
                                                   float* __restrict__ es,
                                                   float* __restrict__ ed, int M) {
    __shared__ u16 As[64][136];   // +8 pad: 2-way bank alias only
    __shared__ u16 Bs[128][136];
    __shared__ float sa_s[128], sa_d[128], cv[128];
    int tid = threadIdx.x;
    if (tid < 128) { sa_s[tid] = avec[tid]; sa_d[tid] = avec[128 + tid]; cv[tid] = cvec[tid]; }
    int row0 = blockIdx.x * 64;
    {
        int n = tid >> 1, k0 = (tid & 1) * 64;
        const uint4* s = (const uint4*)(Wt + (size_t)n * FD + k0);
#pragma unroll
        for (int u = 0; u < 8; u++) *(uint4*)&Bs[n][k0 + u * 8] = s[u];
    }
    {
        int r = tid >> 2, k0 = (tid & 3) * 32;
        int grow = row0 + r;
        if (grow < M) {
            if (use_f32) {
                const float4* s = (const float4*)(Xf + (size_t)grow * FD + k0);
#pragma unroll
                for (int u = 0; u < 8; u++) {
                    float4 v = s[u];
                    ushort4 o;
                    o.x = f2bf(v.x); o.y = f2bf(v.y); o.z = f2bf(v.z); o.w = f2bf(v.w);
                    *(ushort4*)&As[r][k0 + u * 4] = o;
                }
            } else {
                const uint4* s = (const uint4*)(Xb + (size_t)grow * FD + k0);
#pragma unroll
                for (int u = 0; u < 4; u++) *(uint4*)&As[r][k0 + u * 8] = s[u];
            }
        } else {
            uint4 z = make_uint4(0, 0, 0, 0);
#pragma unroll
            for (int u = 0; u < 4; u++) *(uint4*)&As[r][k0 + u * 8] = z;
        }
    }
    __syncthreads();

    int wave = tid >> 6, lane = tid & 63;
    int quad = lane >> 4, n16 = lane & 15;
    int rbase = wave * 16;
    f32x4 acc[8];
    f32x4 zz = {0.f, 0.f, 0.f, 0.f};
#pragma unroll
    for (int t = 0; t < 8; t++) acc[t] = zz;

#pragma unroll
    for (int kk = 0; kk < 128; kk += 32) {
        bf16x8 a = *(const bf16x8*)&As[rbase + n16][kk + quad * 8];
#pragma unroll
        for (int t = 0; t < 8; t++) {
            bf16x8 b = *(const bf16x8*)&Bs[t * 16 + n16][kk + quad * 8];
            acc[t] = __builtin_amdgcn_mfma_f32_16x16x32_bf16(a, b, acc[t], 0, 0, 0);
        }
    }

#pragma unroll
    for (int reg = 0; reg < 4; reg++) {
        int grow = row0 + rbase + quad * 4 + reg;
        float vals[8];
        float ps = 0.f, pd = 0.f;
#pragma unroll
        for (int t = 0; t < 8; t++) {
            float v = acc[t][reg] + cv[t * 16 + n16];
            vals[t] = v;
            ps += v * sa_s[t * 16 + n16];
            pd += v * sa_d[t * 16 + n16];
        }
#pragma unroll
        for (int o = 8; o > 0; o >>= 1) { ps += __shfl_xor(ps, o); pd += __shfl_xor(pd, o); }
        if (grow < M) {
            if (n16 == 0) { es[grow] = ps; ed[grow] = pd; }
            // feature f = t*16+n16 -> plane q=t>>1, within-quarter idx (t&1)*16+n16
#pragma unroll
            for (int t = 0; t < 8; t++)
                Hq[(size_t)(t >> 1) * M * 32 + (size_t)grow * 32 + (t & 1) * 16 + n16] = f2bf(vals[t]);
        }
    }
}

// ---------------------------------------------------------------- edge weights + rowsum (wave per node)
__global__ __launch_bounds__(256) void ee_k(const float* __restrict__ es_,
                                            const float* __restrict__ ed_,
                                            const int* __restrict__ offs,
                                            const int* __restrict__ edst,
                                            float* __restrict__ wbuf,
                                            float* __restrict__ rowsum, int M) {
    int wave = (blockIdx.x * blockDim.x + threadIdx.x) >> 6;
    int lane = threadIdx.x & 63;
    if (wave >= M) return;
    int s0 = offs[wave], s1 = offs[wave + 1];
    float esv = es_[wave];
    float rs = 0.f;
    for (int base = s0; base < s1; base += 64) {
        int m = s1 - base; if (m > 64) m = 64;
        if (lane < m) {
            int d = edst[base + lane];
            float ev = esv + ed_[d];
            float lr = ev > 0.f ? ev : 0.2f * ev;
            float w = __expf(-lr);
            wbuf[base + lane] = w;
            rs += w;
        }
    }
#pragma unroll
    for (int o = 32; o > 0; o >>= 1) rs += __shfl_xor(rs, o);
    if (lane == 0) rowsum[wave] = rs;
}

// ---------------------------------------------------------------- quarter-pinned aggregation
// wave per (node, quarter); q = blockIdx&3 runs on XCDs {q, q+4} (round-robin dispatch),
// so each XCD's gathers stay in its L2-resident 3.2 MB plane. Scalar-pipe edge stream.
// 4 edges per 64B-row gather (16 lanes x dword). Named scalars only (no LDS promotion).
#define QACC(rr, ww) do { \
    acc0 += (ww) * __uint_as_float((rr) << 16); \
    acc1 += (ww) * __uint_as_float((rr) & 0xffff0000u); } while (0)

__global__ __launch_bounds__(256) void agg_q_k(const u16* __restrict__ Hq,
                                               const float* __restrict__ wbuf,
                                               const float* __restrict__ rowsum,
                                               const int* __restrict__ offs,
                                               const int* __restrict__ edst,
                                               u16* __restrict__ Out, int M) {
    int b = blockIdx.x;
    int q = b & 3;
    int r = (b >> 2) & 1;
    int v = b >> 3;
    int wavein = threadIdx.x >> 6;
    int node = __builtin_amdgcn_readfirstlane((v * 2 + r) * 4 + wavein);
    if (node >= M) return;
    int lane = threadIdx.x & 63;
    int g = lane >> 4;      // edge slot 0..3
    int p = lane & 15;      // dword index in the 64B quarter row (2 features)
    int s0 = offs[node], s1 = offs[node + 1];
    const unsigned int* plane = (const unsigned int*)(Hq + (size_t)q * M * 32);
    const int* wbi = (const int*)wbuf;
    float acc0 = 0.f, acc1 = 0.f;
    int e = s0;
    for (; e + 8 <= s1; e += 8) {
        int d0 = __builtin_amdgcn_readfirstlane(edst[e]);
        int d1 = __builtin_amdgcn_readfirstlane(edst[e + 1]);
        int d2 = __builtin_amdgcn_readfirstlane(edst[e + 2]);
        int d3 = __builtin_amdgcn_readfirstlane(edst[e + 3]);
        int d4 = __builtin_amdgcn_readfirstlane(edst[e + 4]);
        int d5 = __builtin_amdgcn_readfirstlane(edst[e + 5]);
        int d6 = __builtin_amdgcn_readfirstlane(edst[e + 6]);
        int d7 = __builtin_amdgcn_readfirstlane(edst[e + 7]);
        float w0 = __int_as_float(__builtin_amdgcn_readfirstlane(wbi[e]));
        float w1 = __int_as_float(__builtin_amdgcn_readfirstlane(wbi[e + 1]));
        float w2 = __int_as_float(__builtin_amdgcn_readfirstlane(wbi[e + 2]));
        float w3 = __int_as_float(__builtin_amdgcn_readfirstlane(wbi[e + 3]));
        float w4 = __int_as_float(__builtin_amdgcn_readfirstlane(wbi[e + 4]));
        float w5 = __int_as_float(__builtin_amdgcn_readfirstlane(wbi[e + 5]));
        float w6 = __int_as_float(__builtin_amdgcn_readfirstlane(wbi[e + 6]));
        float w7 = __int_as_float(__builtin_amdgcn_readfirstlane(wbi[e + 7]));
        int dgA = g == 0 ? d0 : (g == 1 ? d1 : (g == 2 ? d2 : d3));
        int dgB = g == 0 ? d4 : (g == 1 ? d5 : (g == 2 ? d6 : d7));
        float wgA = g == 0 ? w0 : (g == 1 ? w1 : (g == 2 ? w2 : w3));
        float wgB = g == 0 ? w4 : (g == 1 ? w5 : (g == 2 ? w6 : w7));
        unsigned int rA = plane[(size_t)dgA * 16 + p];
        unsigned int rB = plane[(size_t)dgB * 16 + p];
        QACC(rA, wgA);
        QACC(rB, wgB);
    }
    while (e < s1) {
        int m = s1 - e; if (m > 4) m = 4;
        int d0 = __builtin_amdgcn_readfirstlane(edst[e]);
        int d1 = m > 1 ? __builtin_amdgcn_readfirstlane(edst[e + 1]) : d0;
        int d2 = m > 2 ? __builtin_amdgcn_readfirstlane(edst[e + 2]) : d0;
        int d3 = m > 3 ? __builtin_amdgcn_readfirstlane(edst[e + 3]) : d0;
        float w0 = __int_as_float(__builtin_amdgcn_readfirstlane(wbi[e]));
        float w1 = m > 1 ? __int_as_float(__builtin_amdgcn_readfirstlane(wbi[e + 1])) : 0.f;
        float w2 = m > 2 ? __int_as_float(__builtin_amdgcn_readfirstlane(wbi[e + 2])) : 0.f;
        float w3 = m > 3 ? __int_as_float(__builtin_amdgcn_readfirstlane(wbi[e + 3])) : 0.f;
        int dgA = g == 0 ? d0 : (g == 1 ? d1 : (g == 2 ? d2 : d3));
        float wgA = g == 0 ? w0 : (g == 1 ? w1 : (g == 2 ? w2 : w3));
        unsigned int rA = plane[(size_t)dgA * 16 + p];
        QACC(rA, wgA);
        e += m;
    }
    // combine the 4 edge-groups (lanes xor 16, 32 hold same dword p)
#pragma unroll
    for (int o = 16; o < 64; o <<= 1) {
        acc0 += __shfl_xor(acc0, o);
        acc1 += __shfl_xor(acc1, o);
    }
    if (g == 0) {
        float inv = 1.f / (rowsum[node] + 1e-16f);
        float v0 = acc0 * inv, v1 = acc1 * inv;
        v0 = v0 > 0.f ? v0 : (__expf(v0) - 1.f);   // elu
        v1 = v1 > 0.f ? v1 : (__expf(v1) - 1.f);
        ((unsigned int*)Out)[(size_t)node * 64 + q * 16 + p] =
            ((unsigned int)f2bf(v1) << 16) | f2bf(v0);
    }
}

// ---------------------------------------------------------------- BN stats (bf16 input)
__global__ void bnstats_b_k(const u16* __restrict__ Xb, float* __restrict__ sums,
                            float* __restrict__ sumsq, int M) {
    int f = threadIdx.x & 127;
    int half = threadIdx.x >> 7;
    float s1 = 0.f, s2 = 0.f;
    for (int r = blockIdx.x * 2 + half; r < M; r += gridDim.x * 2) {
        float v = bf2f(Xb[(size_t)r * FD + f]);
        s1 += v; s2 += v * v;
    }
    __shared__ float l1[256], l2[256];
    l1[threadIdx.x] = s1; l2[threadIdx.x] = s2;
    __syncthreads();
    if (half == 0) {
        atomicAdd(&sums[f], l1[f] + l1[f + 128]);
        atomicAdd(&sumsq[f], l2[f] + l2[f + 128]);
    }
}

// ---------------------------------------------------------------- pooling (sorted graph ids, bf16 in)
__global__ void pool_k(const u16* __restrict__ Xb, const int* __restrict__ gi,
                       float* __restrict__ pooled, int M) {
    int f = threadIdx.x & 127;
    int half = threadIdx.x >> 7;
    int r0 = blockIdx.x * 128 + half;
    int rend = min(blockIdx.x * 128 + 128, M);
    int curg = -1; float acc = 0.f;
    for (int r = r0; r < rend; r += 2) {
        int g = gi[r];
        if (g != curg) {
            if (curg >= 0) atomicAdd(&pooled[(size_t)curg * FD + f], acc);
            curg = g; acc = 0.f;
        }
        acc += bf2f(Xb[(size_t)r * FD + f]);
    }
    if (curg >= 0) atomicAdd(&pooled[(size_t)curg * FD + f], acc);
}

// ---------------------------------------------------------------- fused MLP (one block per graph)
__global__ __launch_bounds__(256) void mlp_k(const float* __restrict__ pooled,
                                             const float* __restrict__ fc1w, const float* __restrict__ fc1b,
                                             const float* __restrict__ fc2w, const float* __restrict__ fc2b,
                                             const float* __restrict__ fc3w, const float* __restrict__ fc3b,
                                             float* __restrict__ out) {
    int g = blockIdx.x, j = threadIdx.x;
    __shared__ float x[128], t1[256], t2[128], p0[128], p1[128];
    if (j < 128) x[j] = pooled[(size_t)g * FD + j];
    __syncthreads();
    float s = fc1b[j];
    for (int k = 0; k < 128; k++) s += x[k] * fc1w[(size_t)k * 256 + j];
    t1[j] = fmaxf(s, 0.f);
    __syncthreads();
    if (j < 128) {
        float s2 = fc2b[j];
        for (int k = 0; k < 256; k++) s2 += t1[k] * fc2w[(size_t)k * 128 + j];
        t2[j] = fmaxf(s2, 0.f);
    }
    __syncthreads();
    if (j < 128) { p0[j] = t2[j] * fc3w[j * 2]; p1[j] = t2[j] * fc3w[j * 2 + 1]; }
    __syncthreads();
    for (int s3 = 64; s3 > 0; s3 >>= 1) {
        if (j < s3) { p0[j] += p0[j + s3]; p1[j] += p1[j + s3]; }
        __syncthreads();
    }
    if (j == 0) { out[g * 2] = p0[0] + fc3b[0]; out[g * 2 + 1] = p1[0] + fc3b[1]; }
}

// ---------------------------------------------------------------- launcher
extern "C" void kernel_launch(void* const* d_in, const int* in_sizes, int n_in,
                              void* d_out, int out_size, void* d_ws, size_t ws_size,
                              hipStream_t stream) {
    const int*   adj  = (const int*)d_in[0];
    const float* xin  = (const float*)d_in[1];
    const int*   gi   = (const int*)d_in[2];
    const float* W1   = (const float*)d_in[4];
    const float* a1   = (const float*)d_in[5];
    const float* bn2g = (const float*)d_in[6];
    const float* bn2b = (const float*)d_in[7];
    const float* W2   = (const float*)d_in[8];
    const float* a2   = (const float*)d_in[9];
    const float* bn3g = (const float*)d_in[10];
    const float* bn3b = (const float*)d_in[11];
    const float* W3   = (const float*)d_in[12];
    const float* a3   = (const float*)d_in[13];
    const float* fc1w = (const float*)d_in[14];
    const float* fc1b = (const float*)d_in[15];
    const float* fc2w = (const float*)d_in[16];
    const float* fc2b = (const float*)d_in[17];
    const float* fc3w = (const float*)d_in[18];
    const float* fc3b = (const float*)d_in[19];
    float* out = (float*)d_out;

    const int N = N_NODES, E = N_EDGES, G = N_GRAPHS;

    u16*   Xb     = (u16*)d_ws;                   // [N,128] bf16 node features (row-major)
    u16*   Hq     = Xb + (size_t)N * FD;          // 4 quarter-planes [N,32] bf16
    u16*   Wt     = Hq + (size_t)N * FD;          // [128,128] bf16 transposed, BN-folded
    float* es     = (float*)(Wt + FD * FD);       // [N]
    float* ed     = es + N;                       // [N]
    float* rowsum = ed + N;                       // [N]
    float* wbuf   = rowsum + N;                   // [E] edge weights
    float* bnbuf  = wbuf + E;                     // [512]: sumsA, sumsqA, sumsB, sumsqB
    float* sumsA  = bnbuf;
    float* sumsqA = bnbuf + 128;
    float* sumsB  = bnbuf + 256;
    float* sumsqB = bnbuf + 384;
    float* cvec   = bnbuf + 512;                  // [128]
    float* pooled = cvec + FD;                    // [G,128]
    int*   degcnt = (int*)(pooled + (size_t)G * FD); // [N]
    int*   offs   = degcnt + N;                   // [N+1] (padded to N+2)
    int*   cur    = offs + (N + 2);               // [N]
    int*   bsum   = cur + N;                      // [256]
    int*   edst   = bsum + 256;                   // [E] dst per CSR slot

    const int* srcp = adj;
    const int* dstp = adj + E;

    const int NB = (N + 255) / 256;

    // ---- CSR build (once; reused by all 3 layers) — XCD-partitioned
    hipMemsetAsync(degcnt, 0, (size_t)N * sizeof(int), stream);
    count_deg_part_k<<<8 * 392, 256, 0, stream>>>(srcp, degcnt, E);
    scan1_k<<<NB, 256, 0, stream>>>(degcnt, bsum, N, bnbuf, pooled);
    scan3_k<<<NB, 256, 0, stream>>>(degcnt, bsum, offs, cur, N, NB);
    fill_csr_part_k<<<8 * 392, 256, 0, stream>>>(srcp, dstp, cur, edst, E);

    const int gemm_grid = (N + 63) / 64;
    const int wave_grid = (N + 3) / 4;                  // ee: 4 nodes per 256-thread block
    const int aggq_grid = (((N + 3) / 4 + 1) / 2) * 8;  // (node-pairs) x 8 (quarter x replica)
    const float invN = 1.0f / (float)N;

    // ---- layer 1 (fp32 input staged directly; identity affine)
    wprep1_k<<<FD, 128, 0, stream>>>(W1, Wt, cvec);
    gemm_mfma_k<<<gemm_grid, 256, 0, stream>>>(xin, Xb, 1, Wt, cvec, a1, Hq, es, ed, N);
    ee_k<<<wave_grid, 256, 0, stream>>>(es, ed, offs, edst, wbuf, rowsum, N);
    agg_q_k<<<aggq_grid, 256, 0, stream>>>(Hq, wbuf, rowsum, offs, edst, Xb, N);
    bnstats_b_k<<<256, 256, 0, stream>>>(Xb, sumsA, sumsqA, N);

    // ---- layer 2 (BN folded into Wt/cvec)
    bnfw_k<<<FD, 128, 0, stream>>>(W2, sumsA, sumsqA, bn2g, bn2b, invN, Wt, cvec);
    gemm_mfma_k<<<gemm_grid, 256, 0, stream>>>(nullptr, Xb, 0, Wt, cvec, a2, Hq, es, ed, N);
    ee_k<<<wave_grid, 256, 0, stream>>>(es, ed, offs, edst, wbuf, rowsum, N);
    agg_q_k<<<aggq_grid, 256, 0, stream>>>(Hq, wbuf, rowsum, offs, edst, Xb, N);
    bnstats_b_k<<<256, 256, 0, stream>>>(Xb, sumsB, sumsqB, N);

    // ---- layer 3
    bnfw_k<<<FD, 128, 0, stream>>>(W3, sumsB, sumsqB, bn3g, bn3b, invN, Wt, cvec);
    gemm_mfma_k<<<gemm_grid, 256, 0, stream>>>(nullptr, Xb, 0, Wt, cvec, a3, Hq, es, ed, N);
    ee_k<<<wave_grid, 256, 0, stream>>>(es, ed, offs, edst, wbuf, rowsum, N);
    agg_q_k<<<aggq_grid, 256, 0, stream>>>(Hq, wbuf, rowsum, offs, edst, Xb, N);

    // ---- pooling + MLP
    pool_k<<<(N + 127) / 128, 256, 0, stream>>>(Xb, gi, pooled, N);
    mlp_k<<<G, 256, 0, stream>>>(pooled, fc1w, fc1b, fc2w, fc2b, fc3w, fc3b, out);
}

// Round 15
// 426.352 us; speedup vs baseline: 1.3360x; 1.3360x over previous
//
#include <hip/hip_runtime.h>
#include <hip/hip_bf16.h>

#define N_NODES 50000
#define N_EDGES 800000
#define FD 128
#define N_GRAPHS 256
#define NPART 6250   // N_NODES / 8 (nodes per XCD partition)

typedef unsigned short u16;
typedef short bf16x8 __attribute__((ext_vector_type(8)));
typedef float f32x4 __attribute__((ext_vector_type(4)));

__device__ __forceinline__ u16 f2bf(float v) {
    __hip_bfloat16 h = __float2bfloat16(v);
    union { __hip_bfloat16 hh; u16 u; } c; c.hh = h; return c.u;
}
__device__ __forceinline__ float bf2f(u16 r) {
    return __uint_as_float(((unsigned int)r) << 16);
}

// ---------------------------------------------------------------- CSR build (XCD-partitioned)
__global__ __launch_bounds__(256) void count_deg_part_k(const int* __restrict__ src,
                                                        int* __restrict__ cnt, int E) {
    int part = blockIdx.x & 7;
    int lo = part * NPART, hi = lo + NPART;
    int stride = (gridDim.x >> 3) * 256;
    for (int e = (blockIdx.x >> 3) * 256 + threadIdx.x; e < E; e += stride) {
        int s = src[e];
        if (s >= lo && s < hi) atomicAdd(&cnt[s], 1);
    }
}

__global__ __launch_bounds__(256) void fill_csr_part_k(const int* __restrict__ src,
                                                       const int* __restrict__ dst,
                                                       int* __restrict__ cur,
                                                       int* __restrict__ edst, int E) {
    int part = blockIdx.x & 7;
    int lo = part * NPART, hi = lo + NPART;
    int stride = (gridDim.x >> 3) * 256;
    for (int e = (blockIdx.x >> 3) * 256 + threadIdx.x; e < E; e += stride) {
        int s = src[e];
        if (s >= lo && s < hi) {
            int p = atomicAdd(&cur[s], 1);
            edst[p] = dst[e];
        }
    }
}

// per-256-chunk sums; block 0 also zeroes bnbuf (512 f) and pooled (32768 f)
__global__ __launch_bounds__(256) void scan1_k(const int* __restrict__ cnt,
                                               int* __restrict__ bsum, int M,
                                               float* __restrict__ bnbuf,
                                               float* __restrict__ pooled) {
    int i = blockIdx.x * 256 + threadIdx.x;
    int v = (i < M) ? cnt[i] : 0;
    __shared__ int l[256];
    l[threadIdx.x] = v;
    __syncthreads();
    for (int s = 128; s > 0; s >>= 1) {
        if (threadIdx.x < s) l[threadIdx.x] += l[threadIdx.x + s];
        __syncthreads();
    }
    if (threadIdx.x == 0) bsum[blockIdx.x] = l[0];
    if (blockIdx.x == 0) {
        bnbuf[threadIdx.x] = 0.f; bnbuf[threadIdx.x + 256] = 0.f;
        for (int k = threadIdx.x; k < N_GRAPHS * FD; k += 256) pooled[k] = 0.f;
    }
}

// local exclusive scan + redundant per-block scan of raw bsum (merged scan2)
__global__ __launch_bounds__(256) void scan3_k(const int* __restrict__ cnt,
                                               const int* __restrict__ bsum,
                                               int* __restrict__ offs,
                                               int* __restrict__ cur, int M, int NB) {
    int i = blockIdx.x * 256 + threadIdx.x;
    int tid = threadIdx.x;
    __shared__ int bs[256];
    bs[tid] = (tid < NB) ? bsum[tid] : 0;
    __syncthreads();
    for (int off = 1; off < 256; off <<= 1) {
        int t = (tid >= off) ? bs[tid - off] : 0;
        __syncthreads();
        bs[tid] += t;
        __syncthreads();
    }
    int base = (blockIdx.x == 0) ? 0 : bs[blockIdx.x - 1];
    int v = (i < M) ? cnt[i] : 0;
    __shared__ int l[256];
    l[tid] = v;
    __syncthreads();
    for (int off = 1; off < 256; off <<= 1) {
        int t = (tid >= off) ? l[tid - off] : 0;
        __syncthreads();
        l[tid] += t;
        __syncthreads();
    }
    int excl = l[tid] - v + base;
    if (i < M) { offs[i] = excl; cur[i] = excl; }
    if (i == M - 1) offs[M] = excl + v;
}

// ---------------------------------------------------------------- weight prep
// layer 1 (no affine): Wt[n][k] = bf16(W[k][n]); cvec = 0
__global__ __launch_bounds__(128) void wprep1_k(const float* __restrict__ W,
                                                u16* __restrict__ Wt,
                                                float* __restrict__ cvec) {
    int n = blockIdx.x, k = threadIdx.x;
    Wt[(size_t)n * FD + k] = f2bf(W[(size_t)k * FD + n]);
    if (k == 0) cvec[n] = 0.f;
}

// layers 2/3: BN finalize (redundant per block, from sums/sumsq) + weight fold
__global__ __launch_bounds__(128) void bnfw_k(const float* __restrict__ W,
                                              const float* __restrict__ sums,
                                              const float* __restrict__ sumsq,
                                              const float* __restrict__ g,
                                              const float* __restrict__ b,
                                              float invN,
                                              u16* __restrict__ Wt,
                                              float* __restrict__ cvec) {
    int n = blockIdx.x, k = threadIdx.x;
    __shared__ float scs[128], shs[128], l[128];
    float mu = sums[k] * invN;
    float var = sumsq[k] * invN - mu * mu;
    float sc = g[k] * rsqrtf(var + 1e-5f);
    scs[k] = sc;
    shs[k] = b[k] - mu * sc;
    __syncthreads();
    float w = W[(size_t)k * FD + n];
    Wt[(size_t)n * FD + k] = f2bf(scs[k] * w);
    l[k] = shs[k] * w;
    __syncthreads();
    for (int s = 64; s > 0; s >>= 1) {
        if (k < s) l[k] += l[k + s];
        __syncthreads();
    }
    if (k == 0) cvec[n] = l[0];
}

// ---------------------------------------------------------------- MFMA GEMM + dots
__global__ __launch_bounds__(256) void gemm_mfma_k(const float* __restrict__ Xf,
                                                   const u16* __restrict__ Xb,
                                                   int use_f32,
                                                   const u16* __restrict__ Wt,
                                                   const float* __restrict__ cvec,
                                                   const float* __restrict__ avec,
                                                   u16* __restrict__ Hb,
                                                   float* __restrict__ es,
                                                   float* __restrict__ ed, int M) {
    __shared__ u16 As[64][136];   // +8 pad: 2-way bank alias only
    __shared__ u16 Bs[128][136];
    __shared__ float sa_s[128], sa_d[128], cv[128];
    int tid = threadIdx.x;
    if (tid < 128) { sa_s[tid] = avec[tid]; sa_d[tid] = avec[128 + tid]; cv[tid] = cvec[tid]; }
    int row0 = blockIdx.x * 64;
    {
        int n = tid >> 1, k0 = (tid & 1) * 64;
        const uint4* s = (const uint4*)(Wt + (size_t)n * FD + k0);
#pragma unroll
        for (int u = 0; u < 8; u++) *(uint4*)&Bs[n][k0 + u * 8] = s[u];
    }
    {
        int r = tid >> 2, k0 = (tid & 3) * 32;
        int grow = row0 + r;
        if (grow < M) {
            if (use_f32) {
                const float4* s = (const float4*)(Xf + (size_t)grow * FD + k0);
#pragma unroll
                for (int u = 0; u < 8; u++) {
                    float4 v = s[u];
                    ushort4 o;
                    o.x = f2bf(v.x); o.y = f2bf(v.y); o.z = f2bf(v.z); o.w = f2bf(v.w);
                    *(ushort4*)&As[r][k0 + u * 4] = o;
                }
            } else {
                const uint4* s = (const uint4*)(Xb + (size_t)grow * FD + k0);
#pragma unroll
                for (int u = 0; u < 4; u++) *(uint4*)&As[r][k0 + u * 8] = s[u];
            }
        } else {
            uint4 z = make_uint4(0, 0, 0, 0);
#pragma unroll
            for (int u = 0; u < 4; u++) *(uint4*)&As[r][k0 + u * 8] = z;
        }
    }
    __syncthreads();

    int wave = tid >> 6, lane = tid & 63;
    int quad = lane >> 4, n16 = lane & 15;
    int rbase = wave * 16;
    f32x4 acc[8];
    f32x4 zz = {0.f, 0.f, 0.f, 0.f};
#pragma unroll
    for (int t = 0; t < 8; t++) acc[t] = zz;

#pragma unroll
    for (int kk = 0; kk < 128; kk += 32) {
        bf16x8 a = *(const bf16x8*)&As[rbase + n16][kk + quad * 8];
#pragma unroll
        for (int t = 0; t < 8; t++) {
            bf16x8 b = *(const bf16x8*)&Bs[t * 16 + n16][kk + quad * 8];
            acc[t] = __builtin_amdgcn_mfma_f32_16x16x32_bf16(a, b, acc[t], 0, 0, 0);
        }
    }

#pragma unroll
    for (int reg = 0; reg < 4; reg++) {
        int grow = row0 + rbase + quad * 4 + reg;
        float vals[8];
        float ps = 0.f, pd = 0.f;
#pragma unroll
        for (int t = 0; t < 8; t++) {
            float v = acc[t][reg] + cv[t * 16 + n16];
            vals[t] = v;
            ps += v * sa_s[t * 16 + n16];
            pd += v * sa_d[t * 16 + n16];
        }
#pragma unroll
        for (int o = 8; o > 0; o >>= 1) { ps += __shfl_xor(ps, o); pd += __shfl_xor(pd, o); }
        if (grow < M) {
            if (n16 == 0) { es[grow] = ps; ed[grow] = pd; }
#pragma unroll
            for (int t = 0; t < 8; t++)
                Hb[(size_t)grow * FD + t * 16 + n16] = f2bf(vals[t]);
        }
    }
}

// ---------------------------------------------------------------- fused aggregation (round-11 form:
// wave per node, scalar-pipe edge stream, early return, NO barrier/LDS/atomics)
__global__ __launch_bounds__(256) void agg_k(const u16* __restrict__ Hb,
                                             const float* __restrict__ es_,
                                             const float* __restrict__ ed_,
                                             const int* __restrict__ offs,
                                             const int* __restrict__ edst,
                                             u16* __restrict__ Out, int M) {
    int node = __builtin_amdgcn_readfirstlane((int)((blockIdx.x * blockDim.x + threadIdx.x) >> 6));
    int lane = threadIdx.x & 63;
    if (node >= M) return;
    int s0 = offs[node], s1 = offs[node + 1];
    float esv = es_[node];
    const unsigned int* Hrow = (const unsigned int*)Hb;   // one dword = bf16x2 per lane
    float2 a0 = make_float2(0.f, 0.f), a1 = make_float2(0.f, 0.f);
    float2 a2 = make_float2(0.f, 0.f), a3 = make_float2(0.f, 0.f);
    float rs = 0.f;
    int e = s0;
    for (; e + 8 <= s1; e += 8) {
        int d0 = __builtin_amdgcn_readfirstlane(edst[e]);
        int d1 = __builtin_amdgcn_readfirstlane(edst[e + 1]);
        int d2 = __builtin_amdgcn_readfirstlane(edst[e + 2]);
        int d3 = __builtin_amdgcn_readfirstlane(edst[e + 3]);
        int d4 = __builtin_amdgcn_readfirstlane(edst[e + 4]);
        int d5 = __builtin_amdgcn_readfirstlane(edst[e + 5]);
        int d6 = __builtin_amdgcn_readfirstlane(edst[e + 6]);
        int d7 = __builtin_amdgcn_readfirstlane(edst[e + 7]);
        float w0, w1, w2, w3, w4, w5, w6, w7;
        {
            float ev = esv + ed_[d0]; float lr = ev > 0.f ? ev : 0.2f * ev; w0 = __expf(-lr);
        }
        { float ev = esv + ed_[d1]; float lr = ev > 0.f ? ev : 0.2f * ev; w1 = __expf(-lr); }
        { float ev = esv + ed_[d2]; float lr = ev > 0.f ? ev : 0.2f * ev; w2 = __expf(-lr); }
        { float ev = esv + ed_[d3]; float lr = ev > 0.f ? ev : 0.2f * ev; w3 = __expf(-lr); }
        { float ev = esv + ed_[d4]; float lr = ev > 0.f ? ev : 0.2f * ev; w4 = __expf(-lr); }
        { float ev = esv + ed_[d5]; float lr = ev > 0.f ? ev : 0.2f * ev; w5 = __expf(-lr); }
        { float ev = esv + ed_[d6]; float lr = ev > 0.f ? ev : 0.2f * ev; w6 = __expf(-lr); }
        { float ev = esv + ed_[d7]; float lr = ev > 0.f ? ev : 0.2f * ev; w7 = __expf(-lr); }
        unsigned int r0 = Hrow[(size_t)d0 * 64 + lane];
        unsigned int r1 = Hrow[(size_t)d1 * 64 + lane];
        unsigned int r2 = Hrow[(size_t)d2 * 64 + lane];
        unsigned int r3 = Hrow[(size_t)d3 * 64 + lane];
        unsigned int r4 = Hrow[(size_t)d4 * 64 + lane];
        unsigned int r5 = Hrow[(size_t)d5 * 64 + lane];
        unsigned int r6 = Hrow[(size_t)d6 * 64 + lane];
        unsigned int r7 = Hrow[(size_t)d7 * 64 + lane];
        rs += w0 + w1 + w2 + w3 + w4 + w5 + w6 + w7;
        a0.x += w0 * __uint_as_float(r0 << 16);
        a0.y += w0 * __uint_as_float(r0 & 0xffff0000u);
        a1.x += w1 * __uint_as_float(r1 << 16);
        a1.y += w1 * __uint_as_float(r1 & 0xffff0000u);
        a2.x += w2 * __uint_as_float(r2 << 16);
        a2.y += w2 * __uint_as_float(r2 & 0xffff0000u);
        a3.x += w3 * __uint_as_float(r3 << 16);
        a3.y += w3 * __uint_as_float(r3 & 0xffff0000u);
        a0.x += w4 * __uint_as_float(r4 << 16);
        a0.y += w4 * __uint_as_float(r4 & 0xffff0000u);
        a1.x += w5 * __uint_as_float(r5 << 16);
        a1.y += w5 * __uint_as_float(r5 & 0xffff0000u);
        a2.x += w6 * __uint_as_float(r6 << 16);
        a2.y += w6 * __uint_as_float(r6 & 0xffff0000u);
        a3.x += w7 * __uint_as_float(r7 << 16);
        a3.y += w7 * __uint_as_float(r7 & 0xffff0000u);
    }
    for (; e < s1; e++) {
        int d = __builtin_amdgcn_readfirstlane(edst[e]);
        float ev = esv + ed_[d];
        float lr = ev > 0.f ? ev : 0.2f * ev;
        float wv = __expf(-lr);
        rs += wv;
        unsigned int r = Hrow[(size_t)d * 64 + lane];
        a0.x += wv * __uint_as_float(r << 16);
        a0.y += wv * __uint_as_float(r & 0xffff0000u);
    }
    float inv = 1.f / (rs + 1e-16f);
    float vx = (a0.x + a1.x + a2.x + a3.x) * inv;
    float vy = (a0.y + a1.y + a2.y + a3.y) * inv;
    vx = vx > 0.f ? vx : (__expf(vx) - 1.f);   // elu, alpha=1
    vy = vy > 0.f ? vy : (__expf(vy) - 1.f);
    unsigned int pk = ((unsigned int)f2bf(vy) << 16) | f2bf(vx);
    ((unsigned int*)Out)[(size_t)node * 64 + lane] = pk;
}

// ---------------------------------------------------------------- BN stats (bf16 input)
__global__ void bnstats_b_k(const u16* __restrict__ Xb, float* __restrict__ sums,
                            float* __restrict__ sumsq, int M) {
    int f = threadIdx.x & 127;
    int half = threadIdx.x >> 7;
    float s1 = 0.f, s2 = 0.f;
    for (int r = blockIdx.x * 2 + half; r < M; r += gridDim.x * 2) {
        float v = bf2f(Xb[(size_t)r * FD + f]);
        s1 += v; s2 += v * v;
    }
    __shared__ float l1[256], l2[256];
    l1[threadIdx.x] = s1; l2[threadIdx.x] = s2;
    __syncthreads();
    if (half == 0) {
        atomicAdd(&sums[f], l1[f] + l1[f + 128]);
        atomicAdd(&sumsq[f], l2[f] + l2[f + 128]);
    }
}

// ---------------------------------------------------------------- pooling (sorted graph ids, bf16 in)
__global__ void pool_k(const u16* __restrict__ Xb, const int* __restrict__ gi,
                       float* __restrict__ pooled, int M) {
    int f = threadIdx.x & 127;
    int half = threadIdx.x >> 7;
    int r0 = blockIdx.x * 128 + half;
    int rend = min(blockIdx.x * 128 + 128, M);
    int curg = -1; float acc = 0.f;
    for (int r = r0; r < rend; r += 2) {
        int g = gi[r];
        if (g != curg) {
            if (curg >= 0) atomicAdd(&pooled[(size_t)curg * FD + f], acc);
            curg = g; acc = 0.f;
        }
        acc += bf2f(Xb[(size_t)r * FD + f]);
    }
    if (curg >= 0) atomicAdd(&pooled[(size_t)curg * FD + f], acc);
}

// ---------------------------------------------------------------- fused MLP (one block per graph)
__global__ __launch_bounds__(256) void mlp_k(const float* __restrict__ pooled,
                                             const float* __restrict__ fc1w, const float* __restrict__ fc1b,
                                             const float* __restrict__ fc2w, const float* __restrict__ fc2b,
                                             const float* __restrict__ fc3w, const float* __restrict__ fc3b,
                                             float* __restrict__ out) {
    int g = blockIdx.x, j = threadIdx.x;
    __shared__ float x[128], t1[256], t2[128], p0[128], p1[128];
    if (j < 128) x[j] = pooled[(size_t)g * FD + j];
    __syncthreads();
    float s = fc1b[j];
    for (int k = 0; k < 128; k++) s += x[k] * fc1w[(size_t)k * 256 + j];
    t1[j] = fmaxf(s, 0.f);
    __syncthreads();
    if (j < 128) {
        float s2 = fc2b[j];
        for (int k = 0; k < 256; k++) s2 += t1[k] * fc2w[(size_t)k * 128 + j];
        t2[j] = fmaxf(s2, 0.f);
    }
    __syncthreads();
    if (j < 128) { p0[j] = t2[j] * fc3w[j * 2]; p1[j] = t2[j] * fc3w[j * 2 + 1]; }
    __syncthreads();
    for (int s3 = 64; s3 > 0; s3 >>= 1) {
        if (j < s3) { p0[j] += p0[j + s3]; p1[j] += p1[j + s3]; }
        __syncthreads();
    }
    if (j == 0) { out[g * 2] = p0[0] + fc3b[0]; out[g * 2 + 1] = p1[0] + fc3b[1]; }
}

// ---------------------------------------------------------------- launcher
extern "C" void kernel_launch(void* const* d_in, const int* in_sizes, int n_in,
                              void* d_out, int out_size, void* d_ws, size_t ws_size,
                              hipStream_t stream) {
    const int*   adj  = (const int*)d_in[0];
    const float* xin  = (const float*)d_in[1];
    const int*   gi   = (const int*)d_in[2];
    const float* W1   = (const float*)d_in[4];
    const float* a1   = (const float*)d_in[5];
    const float* bn2g = (const float*)d_in[6];
    const float* bn2b = (const float*)d_in[7];
    const float* W2   = (const float*)d_in[8];
    const float* a2   = (const float*)d_in[9];
    const float* bn3g = (const float*)d_in[10];
    const float* bn3b = (const float*)d_in[11];
    const float* W3   = (const float*)d_in[12];
    const float* a3   = (const float*)d_in[13];
    const float* fc1w = (const float*)d_in[14];
    const float* fc1b = (const float*)d_in[15];
    const float* fc2w = (const float*)d_in[16];
    const float* fc2b = (const float*)d_in[17];
    const float* fc3w = (const float*)d_in[18];
    const float* fc3b = (const float*)d_in[19];
    float* out = (float*)d_out;

    const int N = N_NODES, E = N_EDGES, G = N_GRAPHS;

    u16*   Xb     = (u16*)d_ws;                   // [N,128] bf16 node features
    u16*   Hb     = Xb + (size_t)N * FD;          // [N,128] bf16 post-GEMM
    u16*   Wt     = Hb + (size_t)N * FD;          // [128,128] bf16 transposed, BN-folded
    float* es     = (float*)(Wt + FD * FD);       // [N]
    float* ed     = es + N;                       // [N]
    float* bnbuf  = ed + N;                       // [512]: sumsA, sumsqA, sumsB, sumsqB
    float* sumsA  = bnbuf;
    float* sumsqA = bnbuf + 128;
    float* sumsB  = bnbuf + 256;
    float* sumsqB = bnbuf + 384;
    float* cvec   = bnbuf + 512;                  // [128]
    float* pooled = cvec + FD;                    // [G,128]
    int*   degcnt = (int*)(pooled + (size_t)G * FD); // [N]
    int*   offs   = degcnt + N;                   // [N+1] (padded to N+2)
    int*   cur    = offs + (N + 2);               // [N]
    int*   bsum   = cur + N;                      // [256]
    int*   edst   = bsum + 256;                   // [E] dst per CSR slot

    const int* srcp = adj;
    const int* dstp = adj + E;

    const int NB = (N + 255) / 256;

    // ---- CSR build (once; reused by all 3 layers) — XCD-partitioned
    hipMemsetAsync(degcnt, 0, (size_t)N * sizeof(int), stream);
    count_deg_part_k<<<8 * 392, 256, 0, stream>>>(srcp, degcnt, E);
    scan1_k<<<NB, 256, 0, stream>>>(degcnt, bsum, N, bnbuf, pooled);
    scan3_k<<<NB, 256, 0, stream>>>(degcnt, bsum, offs, cur, N, NB);
    fill_csr_part_k<<<8 * 392, 256, 0, stream>>>(srcp, dstp, cur, edst, E);

    const int gemm_grid = (N + 63) / 64;
    const int wave_grid = (N + 3) / 4;      // 4 waves per 256-thread block
    const float invN = 1.0f / (float)N;

    // ---- layer 1 (fp32 input staged directly; identity affine)
    wprep1_k<<<FD, 128, 0, stream>>>(W1, Wt, cvec);
    gemm_mfma_k<<<gemm_grid, 256, 0, stream>>>(xin, Xb, 1, Wt, cvec, a1, Hb, es, ed, N);
    agg_k<<<wave_grid, 256, 0, stream>>>(Hb, es, ed, offs, edst, Xb, N);
    bnstats_b_k<<<256, 256, 0, stream>>>(Xb, sumsA, sumsqA, N);

    // ---- layer 2 (BN folded into Wt/cvec)
    bnfw_k<<<FD, 128, 0, stream>>>(W2, sumsA, sumsqA, bn2g, bn2b, invN, Wt, cvec);
    gemm_mfma_k<<<gemm_grid, 256, 0, stream>>>(nullptr, Xb, 0, Wt, cvec, a2, Hb, es, ed, N);
    agg_k<<<wave_grid, 256, 0, stream>>>(Hb, es, ed, offs, edst, Xb, N);
    bnstats_b_k<<<256, 256, 0, stream>>>(Xb, sumsB, sumsqB, N);

    // ---- layer 3
    bnfw_k<<<FD, 128, 0, stream>>>(W3, sumsB, sumsqB, bn3g, bn3b, invN, Wt, cvec);
    gemm_mfma_k<<<gemm_grid, 256, 0, stream>>>(nullptr, Xb, 0, Wt, cvec, a3, Hb, es, ed, N);
    agg_k<<<wave_grid, 256, 0, stream>>>(Hb, es, ed, offs, edst, Xb, N);

    // ---- pooling + MLP
    pool_k<<<(N + 127) / 128, 256, 0, stream>>>(Xb, gi, pooled, N);
    mlp_k<<<G, 256, 0, stream>>>(pooled, fc1w, fc1b, fc2w, fc2b, fc3w, fc3b, out);
}